// Round 1
// baseline (98.593 us; speedup 1.0000x reference)
//
#include <hip/hip_runtime.h>
#include <hip/hip_bf16.h>
#include <math.h>

#define B_ROWS 8192
#define K_DIM  128
#define LAMBDA_KL 1.0
#define LAMBDA_LOGDET 0.01
#define JITTER 1e-6

// digamma(x), x > 0. Shift to x >= 6, then asymptotic series.
__device__ __forceinline__ double digamma_d(double x) {
    double r = 0.0;
    while (x < 6.0) { r -= 1.0 / x; x += 1.0; }
    double xi = 1.0 / x;
    double f  = xi * xi;
    double p = f * (-1.0/12.0 + f * (1.0/120.0 + f * (-1.0/252.0
               + f * (1.0/240.0 + f * (-1.0/132.0)))));
    return r + log(x) - 0.5 * xi + p;
}

// trigamma(x) = polygamma(1, x), x > 0.
__device__ __forceinline__ double trigamma_d(double x) {
    double r = 0.0;
    while (x < 6.0) { double xi = 1.0 / x; r += xi * xi; x += 1.0; }
    double xi = 1.0 / x;
    double f  = xi * xi;
    double p = xi + 0.5 * f + xi * f * (1.0/6.0 + f * (-1.0/30.0
               + f * (1.0/42.0 + f * (-1.0/30.0 + f * (5.0/66.0)))));
    return r + p;
}

// One wave per row. Lane handles elements lane and lane+64.
__global__ __launch_bounds__(64)
void iedl_row_kernel(const float* __restrict__ alpha,
                     const int* __restrict__ target,
                     double* __restrict__ ws) {
    const int b    = blockIdx.x;
    const int lane = threadIdx.x;          // 0..63
    const float* arow = alpha + (size_t)b * K_DIM;

    const float a0f = arow[lane];
    const float a1f = arow[lane + 64];
    const int   tgt = target[b];

    const double a0 = (double)a0f;
    const double a1 = (double)a1f;

    // ---- row sum S (butterfly: all lanes end with identical value) ----
    double s = a0 + a1;
    #pragma unroll
    for (int m = 1; m < 64; m <<= 1) s += __shfl_xor(s, m);

    const double a_t    = (double)arow[tgt];   // broadcast load
    const double s_hat  = s - a_t + 1.0;
    const double trig_s = trigamma_d(s);
    const double dg_sh  = digamma_d(s_hat);

    double mse_sum = 0.0, kl_sum = 0.0, logd_sum = 0.0, invd_sum = 0.0;

    #pragma unroll
    for (int e = 0; e < 2; ++e) {
        const int    k  = lane + e * 64;
        const double ad = (e == 0) ? a0 : a1;

        const double trig_a = trigamma_d(ad);

        // i_mse terms
        const double p   = ad / s;
        const double y   = (k == tgt) ? 1.0 : 0.0;
        const double err = (y - p) * (y - p);
        const double var = p * (1.0 - p) / (s + 1.0);
        double w = trig_a - trig_s;
        if (w < 1e-8) w = 1e-8;
        mse_sum += w * (err + var);

        // KL terms (target element: alpha_hat = 1 contributes exactly 0)
        if (k != tgt) {
            kl_sum += -lgamma(ad) + (ad - 1.0) * (digamma_d(ad) - dg_sh);
        }

        // logdet terms: D_i = trigamma(alpha_i) + jitter
        const double D = trig_a + JITTER;
        logd_sum += log(D);
        invd_sum += 1.0 / D;
    }

    #pragma unroll
    for (int m = 1; m < 64; m <<= 1) {
        mse_sum  += __shfl_xor(mse_sum,  m);
        kl_sum   += __shfl_xor(kl_sum,   m);
        logd_sum += __shfl_xor(logd_sum, m);
        invd_sum += __shfl_xor(invd_sum, m);
    }

    if (lane == 0) {
        // KL per-sample
        const double kl_row = lgamma(s_hat) - lgamma((double)K_DIM) + kl_sum;
        // matrix determinant lemma: det = prod(D) * (1 - c * sum(1/D)); det(D)>0
        const double t = 1.0 - trig_s * invd_sum;
        const double logdet_row = (t > 0.0) ? (logd_sum + log(t)) : -20.0;
        ws[b]              = mse_sum;
        ws[B_ROWS + b]     = kl_row;
        ws[2 * B_ROWS + b] = logdet_row;
    }
}

__global__ __launch_bounds__(256)
void iedl_reduce_kernel(const double* __restrict__ ws, float* __restrict__ out) {
    const int tid = threadIdx.x;
    double m = 0.0, k = 0.0, l = 0.0;
    for (int i = tid; i < B_ROWS; i += 256) {
        m += ws[i];
        k += ws[B_ROWS + i];
        l += ws[2 * B_ROWS + i];
    }
    #pragma unroll
    for (int off = 1; off < 64; off <<= 1) {
        m += __shfl_xor(m, off);
        k += __shfl_xor(k, off);
        l += __shfl_xor(l, off);
    }
    __shared__ double sm[3][4];
    const int wid = tid >> 6;
    if ((tid & 63) == 0) { sm[0][wid] = m; sm[1][wid] = k; sm[2][wid] = l; }
    __syncthreads();
    if (tid == 0) {
        double M = 0.0, KK = 0.0, L = 0.0;
        #pragma unroll
        for (int w = 0; w < 4; ++w) { M += sm[0][w]; KK += sm[1][w]; L += sm[2][w]; }
        const double inv_b  = 1.0 / (double)B_ROWS;
        const double i_mse  = M * inv_b;
        const double kl     = KK * inv_b;
        const double ldm    = L * inv_b;
        const double total  = i_mse + LAMBDA_KL * kl - LAMBDA_LOGDET * ldm;
        out[0] = (float)total;
        out[1] = (float)i_mse;
        out[2] = (float)kl;
        out[3] = (float)ldm;
    }
}

extern "C" void kernel_launch(void* const* d_in, const int* in_sizes, int n_in,
                              void* d_out, int out_size, void* d_ws, size_t ws_size,
                              hipStream_t stream) {
    const float* alpha  = (const float*)d_in[0];
    const int*   target = (const int*)d_in[1];
    float*       out    = (float*)d_out;
    double*      ws     = (double*)d_ws;   // 3 * 8192 doubles = 192 KiB

    iedl_row_kernel<<<B_ROWS, 64, 0, stream>>>(alpha, target, ws);
    iedl_reduce_kernel<<<1, 256, 0, stream>>>(ws, out);
}

// Round 3
// 63.724 us; speedup vs baseline: 1.5472x; 1.5472x over previous
//
#include <hip/hip_runtime.h>
#include <hip/hip_bf16.h>
#include <math.h>

#define B_ROWS 8192
#define K_DIM  128
#define LAMBDA_KL 1.0f
#define LAMBDA_LOGDET 0.01f
#define JITTER 1e-6f

__device__ __forceinline__ float rcpf(float x) { return __builtin_amdgcn_rcpf(x); }

// Fused digamma / trigamma / lgamma for x in [0.5, 5).
// Fixed 6-step shift (branch-free): y = x+6 in [6.5, 11), asymptotic series there.
__device__ __forceinline__ void special3(float x, float& dg, float& tg, float& lg) {
    const float x1 = x + 1.f, x2 = x + 2.f, x3 = x + 3.f, x4 = x + 4.f, x5 = x + 5.f;
    const float r0 = rcpf(x),  r1 = rcpf(x1), r2 = rcpf(x2);
    const float r3 = rcpf(x3), r4 = rcpf(x4), r5 = rcpf(x5);
    const float y  = x + 6.f;
    const float iy = rcpf(y);
    const float f  = iy * iy;
    const float ly = __logf(y);

    // digamma(y) = ln y - 1/(2y) - 1/(12y^2) + 1/(120y^4) - 1/(252y^6)
    const float dg_y = ly - 0.5f * iy
                     + f * (-1.f/12.f + f * (1.f/120.f + f * (-1.f/252.f)));
    dg = dg_y - (((r0 + r1) + (r2 + r3)) + (r4 + r5));

    // trigamma(y) = 1/y + 1/(2y^2) + 1/(6y^3) - 1/(30y^5) + 1/(42y^7)
    const float tg_y = iy * (1.f + iy * (0.5f + iy * (1.f/6.f
                     + f * (-1.f/30.f + f * (1.f/42.f)))));
    tg = tg_y + (((r0*r0 + r1*r1) + (r2*r2 + r3*r3)) + (r4*r4 + r5*r5));

    // lgamma(y) by Stirling, then remove the shift: lgamma(x) = lgamma(y) - ln(x(x+1)...(x+5))
    const float lg_y = (y - 0.5f) * ly - y + 0.91893853320467274f
                     + iy * (1.f/12.f + f * (-1.f/360.f + f * (1.f/1260.f)));
    const float prod = ((x * x1) * (x2 * x3)) * (x4 * x5);
    lg = lg_y - __logf(prod);
}

// Large-argument (>= 60) direct asymptotics.
__device__ __forceinline__ float digamma_big(float y) {
    const float iy = rcpf(y), f = iy * iy;
    return __logf(y) - 0.5f * iy - f * (1.f/12.f);
}
__device__ __forceinline__ float trigamma_big(float y) {
    const float iy = rcpf(y), f = iy * iy;
    return iy + 0.5f * f + f * iy * (1.f/6.f);
}
__device__ __forceinline__ float lgamma_big(float y) {
    const float iy = rcpf(y);
    return (y - 0.5f) * __logf(y) - y + 0.91893853320467274f + iy * (1.f/12.f);
}

// 256 threads = 4 waves; wave w handles row blockIdx.x*4 + w. Lane holds 2
// consecutive elements via one float2 load.
__global__ __launch_bounds__(256)
void iedl_row_kernel(const float* __restrict__ alpha,
                     const int* __restrict__ target,
                     float* __restrict__ ws) {
    const int wave = threadIdx.x >> 6;
    const int lane = threadIdx.x & 63;
    const int b    = blockIdx.x * 4 + wave;

    const float2 a2 = ((const float2*)(alpha + (size_t)b * K_DIM))[lane];
    const int    tgt = target[b];

    // ---- row sum S (butterfly; all lanes identical) ----
    float s = a2.x + a2.y;
    #pragma unroll
    for (int m = 1; m < 64; m <<= 1) s += __shfl_xor(s, m);

    // alpha[tgt] via shuffle from owning lane (tgt is wave-uniform)
    const float a_pick = (tgt & 1) ? a2.y : a2.x;
    const float a_t    = __shfl(a_pick, tgt >> 1);

    const float s_hat  = s - a_t + 1.f;           // large (~350)
    const float trig_s = trigamma_big(s);
    const float dg_sh  = digamma_big(s_hat);
    const float inv_s  = rcpf(s);
    const float inv_s1 = rcpf(s + 1.f);

    float mse_sum = 0.f, kl_sum = 0.f, logd_sum = 0.f, invd_sum = 0.f;

    #pragma unroll
    for (int e = 0; e < 2; ++e) {
        const int   k  = 2 * lane + e;
        const float ad = (e == 0) ? a2.x : a2.y;

        float dg_a, tg_a, lg_a;
        special3(ad, dg_a, tg_a, lg_a);

        // i_mse terms
        const float p   = ad * inv_s;
        const float y1  = (k == tgt) ? 1.f : 0.f;
        const float err = (y1 - p) * (y1 - p);
        const float var = p * (1.f - p) * inv_s1;
        const float w   = fmaxf(tg_a - trig_s, 1e-8f);
        mse_sum += w * (err + var);

        // KL terms; target element (alpha_hat=1) contributes exactly 0
        if (k != tgt) kl_sum += -lg_a + (ad - 1.f) * (dg_a - dg_sh);

        // logdet terms: D = trigamma(alpha) + jitter
        const float D = tg_a + JITTER;
        logd_sum += __logf(D);
        invd_sum += rcpf(D);
    }

    #pragma unroll
    for (int m = 1; m < 64; m <<= 1) {
        mse_sum  += __shfl_xor(mse_sum,  m);
        kl_sum   += __shfl_xor(kl_sum,   m);
        logd_sum += __shfl_xor(logd_sum, m);
        invd_sum += __shfl_xor(invd_sum, m);
    }

    if (lane == 0) {
        // lgamma(128) = 491.5534482309... (Stirling at y=128; was wrong in R2)
        const float kl_row = lgamma_big(s_hat) - 491.5534482f + kl_sum;
        // det(FIM) = prod(D) * (1 - trig_s * sum(1/D))  (diag + rank-1)
        const float t = 1.f - trig_s * invd_sum;
        const float logdet_row = (t > 0.f) ? (logd_sum + __logf(t)) : -20.f;
        ws[b]              = mse_sum;
        ws[B_ROWS + b]     = kl_row;
        ws[2 * B_ROWS + b] = logdet_row;
    }
}

__global__ __launch_bounds__(1024)
void iedl_reduce_kernel(const float* __restrict__ ws, float* __restrict__ out) {
    const int tid = threadIdx.x;
    float m = 0.f, k = 0.f, l = 0.f;
    #pragma unroll
    for (int i = 0; i < B_ROWS / 1024; ++i) {
        const int idx = tid + i * 1024;
        m += ws[idx];
        k += ws[B_ROWS + idx];
        l += ws[2 * B_ROWS + idx];
    }
    double md = m, kd = k, ld = l;
    #pragma unroll
    for (int off = 1; off < 64; off <<= 1) {
        md += __shfl_xor(md, off);
        kd += __shfl_xor(kd, off);
        ld += __shfl_xor(ld, off);
    }
    __shared__ double sm[3][16];
    const int wid = tid >> 6;
    if ((tid & 63) == 0) { sm[0][wid] = md; sm[1][wid] = kd; sm[2][wid] = ld; }
    __syncthreads();
    if (tid == 0) {
        double M = 0.0, KK = 0.0, L = 0.0;
        #pragma unroll
        for (int w = 0; w < 16; ++w) { M += sm[0][w]; KK += sm[1][w]; L += sm[2][w]; }
        const double inv_b = 1.0 / (double)B_ROWS;
        const double i_mse = M * inv_b;
        const double kl    = KK * inv_b;
        const double ldm   = L * inv_b;
        out[0] = (float)(i_mse + (double)LAMBDA_KL * kl - (double)LAMBDA_LOGDET * ldm);
        out[1] = (float)i_mse;
        out[2] = (float)kl;
        out[3] = (float)ldm;
    }
}

extern "C" void kernel_launch(void* const* d_in, const int* in_sizes, int n_in,
                              void* d_out, int out_size, void* d_ws, size_t ws_size,
                              hipStream_t stream) {
    const float* alpha  = (const float*)d_in[0];
    const int*   target = (const int*)d_in[1];
    float*       out    = (float*)d_out;
    float*       ws     = (float*)d_ws;   // 3 * 8192 floats = 96 KiB

    iedl_row_kernel<<<B_ROWS / 4, 256, 0, stream>>>(alpha, target, ws);
    iedl_reduce_kernel<<<1, 1024, 0, stream>>>(ws, out);
}